// Round 1
// baseline (12655.202 us; speedup 1.0000x reference)
//
#include <hip/hip_runtime.h>

#define N_TOK 65536
#define DIM   256
#define KCB   1024
#define LVL   8
#define TPB   16      // tokens per block
#define MARGIN 0.125f

// f64 exact distance ||r - c||^2. __noinline__ so both refine phases call the
// SAME code and get bit-identical results.
__device__ __noinline__ double dist64(const double* __restrict__ r,
                                      const float* __restrict__ crow) {
    double s0 = 0.0, s1 = 0.0;
    for (int d = 0; d < DIM; d += 2) {
        double a = r[d]     - (double)crow[d];
        double b = r[d + 1] - (double)crow[d + 1];
        s0 += a * a;
        s1 += b * b;
    }
    return s0 + s1;
}

// csq[l*KCB + k] = sum_d cb[l][k][d]^2  (f32; only feeds the fast pass,
// refine recomputes in f64 so precision here is uncritical)
__global__ void csq_kernel(const float* __restrict__ cb, float* __restrict__ csq) {
    const int lane = threadIdx.x & 63;
    const int wid  = (blockIdx.x * blockDim.x + threadIdx.x) >> 6;
    const int nw   = (gridDim.x * blockDim.x) >> 6;
    for (int row = wid; row < LVL * KCB; row += nw) {
        float4 c = *(const float4*)(cb + (long)row * DIM + lane * 4);
        float s = c.x * c.x + c.y * c.y + c.z * c.z + c.w * c.w;
        for (int off = 32; off; off >>= 1) s += __shfl_xor(s, off);
        if (lane == 0) csq[row] = s;
    }
}

__global__ __launch_bounds__(256) void rvq_kernel(const float* __restrict__ x,
                                                  const float* __restrict__ cb,
                                                  const float* __restrict__ csq,
                                                  float* __restrict__ out) {
    __shared__ double r64[TPB * DIM];                 // 32 KB residual (f64, exact)
    __shared__ float  r32[TPB * DIM];                 // 16 KB f32 copy for fast pass
    __shared__ float  wval[4][TPB];
    __shared__ int    widx[4][TPB];
    __shared__ float  minv[TPB];
    __shared__ unsigned long long dbits[TPB];
    __shared__ int    dmin_idx[TPB];
    __shared__ int    codes_s[TPB][LVL];

    const int tid  = threadIdx.x;
    const int wave = tid >> 6;
    const int lane = tid & 63;
    const long tok0 = (long)blockIdx.x * TPB;
    const float* xblk = x + tok0 * DIM;

    // load x tile -> residual
    for (int i = 0; i < TPB; i++) {
        float v = xblk[i * DIM + tid];
        r64[i * DIM + tid] = (double)v;
        r32[i * DIM + tid] = v;
    }
    __syncthreads();

    const int k0 = wave * 256 + lane * 4;   // this lane's 4 contiguous codewords

    for (int l = 0; l < LVL; l++) {
        const float* cbl = cb + (long)l * KCB * DIM;

        // ---- fast pass: f32 dot(r, c) for 4 codewords x 16 tokens ----
        float acc[4][TPB];
        #pragma unroll
        for (int j = 0; j < 4; j++)
            #pragma unroll
            for (int t = 0; t < TPB; t++) acc[j][t] = 0.f;

        for (int d0 = 0; d0 < DIM; d0 += 4) {
            float4 c4[4];
            #pragma unroll
            for (int j = 0; j < 4; j++)
                c4[j] = *(const float4*)(cbl + (long)(k0 + j) * DIM + d0);
            #pragma unroll
            for (int t = 0; t < TPB; t++) {
                float4 r4 = *(const float4*)(r32 + t * DIM + d0);  // wave-broadcast
                #pragma unroll
                for (int j = 0; j < 4; j++) {
                    acc[j][t] = fmaf(c4[j].x, r4.x, acc[j][t]);
                    acc[j][t] = fmaf(c4[j].y, r4.y, acc[j][t]);
                    acc[j][t] = fmaf(c4[j].z, r4.z, acc[j][t]);
                    acc[j][t] = fmaf(c4[j].w, r4.w, acc[j][t]);
                }
            }
        }
        // score = ||c||^2 - 2 r.c   (argmin-equivalent; r_sq is per-token const)
        float cs[4];
        #pragma unroll
        for (int j = 0; j < 4; j++) cs[j] = csq[l * KCB + k0 + j];
        #pragma unroll
        for (int j = 0; j < 4; j++)
            #pragma unroll
            for (int t = 0; t < TPB; t++)
                acc[j][t] = cs[j] - 2.0f * acc[j][t];

        // ---- f32 argmin: lane -> wave (shuffle) -> block ----
        #pragma unroll
        for (int t = 0; t < TPB; t++) {
            float bv = acc[0][t];
            int   bi = k0;
            #pragma unroll
            for (int j = 1; j < 4; j++)
                if (acc[j][t] < bv) { bv = acc[j][t]; bi = k0 + j; }
            for (int off = 1; off < 64; off <<= 1) {
                float ov = __shfl_xor(bv, off);
                int   oi = __shfl_xor(bi, off);
                if (ov < bv || (ov == bv && oi < bi)) { bv = ov; bi = oi; }
            }
            if (lane == 0) { wval[wave][t] = bv; widx[wave][t] = bi; }
        }
        __syncthreads();
        if (tid < TPB) {
            float m = wval[0][tid];
            for (int w = 1; w < 4; w++) m = fminf(m, wval[w][tid]);
            minv[tid]     = m;
            dbits[tid]    = 0xFFFFFFFFFFFFFFFFULL;
            dmin_idx[tid] = KCB;
        }
        __syncthreads();

        // ---- refine: every candidate within MARGIN of the f32 min gets an
        // exact f64 distance; pick f64 min, tie-break lowest index ----
        #pragma unroll
        for (int t = 0; t < TPB; t++) {
            float thr = minv[t] + MARGIN;
            #pragma unroll
            for (int j = 0; j < 4; j++) {
                if (acc[j][t] <= thr) {
                    double d64 = dist64(r64 + t * DIM, cbl + (long)(k0 + j) * DIM);
                    atomicMin(&dbits[t], (unsigned long long)__double_as_longlong(d64));
                }
            }
        }
        __syncthreads();
        #pragma unroll
        for (int t = 0; t < TPB; t++) {
            float thr = minv[t] + MARGIN;
            #pragma unroll
            for (int j = 0; j < 4; j++) {
                if (acc[j][t] <= thr) {
                    double d64 = dist64(r64 + t * DIM, cbl + (long)(k0 + j) * DIM);
                    if ((unsigned long long)__double_as_longlong(d64) == dbits[t])
                        atomicMin(&dmin_idx[t], k0 + j);
                }
            }
        }
        __syncthreads();

        if (tid < TPB) codes_s[tid][l] = dmin_idx[tid];

        // ---- residual update (f64 exact) ----
        for (int i = 0; i < TPB; i++) {
            int k = dmin_idx[i];
            float c = cbl[(long)k * DIM + tid];
            double nr = r64[i * DIM + tid] - (double)c;
            r64[i * DIM + tid] = nr;
            r32[i * DIM + tid] = (float)nr;
        }
        __syncthreads();
    }

    // ---- outputs: quantized = x - residual_final; codes as float ----
    for (int i = 0; i < TPB; i++) {
        double q = (double)xblk[i * DIM + tid] - r64[i * DIM + tid];
        out[tok0 * DIM + i * DIM + tid] = (float)q;
    }
    float* cout = out + (long)N_TOK * DIM;
    if (tid < TPB * LVL) {
        int t = tid >> 3, l = tid & 7;
        cout[(tok0 + t) * LVL + l] = (float)codes_s[t][l];
    }
}

extern "C" void kernel_launch(void* const* d_in, const int* in_sizes, int n_in,
                              void* d_out, int out_size, void* d_ws, size_t ws_size,
                              hipStream_t stream) {
    const float* x  = (const float*)d_in[0];
    const float* cb = (const float*)d_in[1];
    float* csq = (float*)d_ws;                       // 8192 floats = 32 KB
    csq_kernel<<<32, 256, 0, stream>>>(cb, csq);
    rvq_kernel<<<N_TOK / TPB, 256, 0, stream>>>(x, cb, csq, (float*)d_out);
}

// Round 2
// 8108.698 us; speedup vs baseline: 1.5607x; 1.5607x over previous
//
#include <hip/hip_runtime.h>

#define N_TOK 65536
#define DIM   256
#define KCB   1024
#define LVL   8
#define TPB   16
#define MARGIN_STAR 0.0625f   // on score* = r.c - 0.5||c||^2  (score = -2*score*)
#define MARGIN_F32  0.125f    // fallback path margin on score = ||c||^2 - 2 r.c

typedef __attribute__((ext_vector_type(8))) short bf16x8;
typedef __attribute__((ext_vector_type(4))) float f32x4;

static __device__ inline unsigned short f2bf(float f) {
    unsigned u = __float_as_uint(f);
    unsigned r = u + 0x7FFFu + ((u >> 16) & 1u);   // RNE
    return (unsigned short)(r >> 16);
}
static __device__ inline float bf2f(unsigned short h) {
    return __uint_as_float(((unsigned)h) << 16);
}

// f64 exact distance ||r - c||^2. __noinline__ so every call site produces
// bit-identical results (single code instance).
__device__ __noinline__ double dist64(const double* r, const float* crow) {
    double s0 = 0.0, s1 = 0.0;
    for (int d = 0; d < DIM; d += 2) {
        double a = r[d]     - (double)crow[d];
        double b = r[d + 1] - (double)crow[d + 1];
        s0 += a * a;
        s1 += b * b;
    }
    return s0 + s1;
}

// ---------------- pack: codebook -> B-fragment-linear bf16 hi/lo ----------------
// frag id f = (l*64 + n)*8 + kk ; 2KB per frag: [hi 1KB][lo 1KB], lane-linear.
// value(lane, j) = cb[l][n*16 + (lane&15)][kk*32 + (lane>>4)*8 + j]
__global__ void pack_kernel(const float* __restrict__ cb, short* __restrict__ packed) {
    const int lane = threadIdx.x & 63;
    const int fid  = (blockIdx.x * blockDim.x + threadIdx.x) >> 6;  // 0..4095
    const int l  = fid >> 9;
    const int n  = (fid >> 3) & 63;
    const int kk = fid & 7;
    const int col = n * 16 + (lane & 15);
    const int kb  = kk * 32 + (lane >> 4) * 8;
    const float* src = cb + ((long)(l * KCB + col)) * DIM + kb;
    float4 f0 = *(const float4*)src;
    float4 f1 = *(const float4*)(src + 4);
    float fv[8] = {f0.x, f0.y, f0.z, f0.w, f1.x, f1.y, f1.z, f1.w};
    union { unsigned short s[8]; int4 v; } H, L;
    #pragma unroll
    for (int j = 0; j < 8; j++) {
        unsigned short h = f2bf(fv[j]);
        H.s[j] = h;
        L.s[j] = f2bf(fv[j] - bf2f(h));
    }
    short* dst = packed + (long)fid * 1024 + lane * 8;
    *(int4*)dst         = H.v;
    *(int4*)(dst + 512) = L.v;
}

// bias[l*K + k] = -0.5 * ||cb[l][k]||^2  (f32; refine is f64-exact anyway)
__global__ void bias_kernel(const float* __restrict__ cb, float* __restrict__ bias) {
    const int lane = threadIdx.x & 63;
    const int wid  = (blockIdx.x * blockDim.x + threadIdx.x) >> 6;
    const int nw   = (gridDim.x * blockDim.x) >> 6;
    for (int row = wid; row < LVL * KCB; row += nw) {
        float4 c = *(const float4*)(cb + (long)row * DIM + lane * 4);
        float s = c.x * c.x + c.y * c.y + c.z * c.z + c.w * c.w;
        for (int off = 32; off; off >>= 1) s += __shfl_xor(s, off);
        if (lane == 0) bias[row] = -0.5f * s;
    }
}

// ---------------- main: MFMA scores + exact f64 refine ----------------
__global__ __launch_bounds__(256, 2) void rvq_mfma(const float* __restrict__ x,
                                                   const float* __restrict__ cb,
                                                   const short* __restrict__ packed,
                                                   const float* __restrict__ bias,
                                                   float* __restrict__ out) {
    __shared__ double r64[TPB * DIM];     // 32 KB exact residual
    __shared__ short  abufH[8 * 64 * 8];  // 8 KB A-fragments (hi), fragment-linear
    __shared__ short  abufL[8 * 64 * 8];  // 8 KB A-fragments (lo)
    __shared__ float  wmax[4][TPB];
    __shared__ float  maxv[TPB];
    __shared__ unsigned long long dbits[TPB];
    __shared__ int    dmin[TPB];
    __shared__ int    codes_s[TPB][LVL];

    const int tid  = threadIdx.x;
    const int w    = tid >> 6;
    const int lane = tid & 63;
    const long tok0 = (long)blockIdx.x * TPB;
    const float* xblk = x + tok0 * DIM;

    // init residual (f64 exact)
    {
        const int tok = tid >> 4, d0 = (tid & 15) * 16;
        for (int i = 0; i < 16; i++)
            r64[tok * DIM + d0 + i] = (double)xblk[tok * DIM + d0 + i];
    }
    __syncthreads();

    for (int l = 0; l < LVL; l++) {
        // ---- A conversion: r64 -> bf16 hi/lo fragments (fragment-linear LDS) ----
        {
            const int tok = tid >> 4, k0 = (tid & 15) * 16;
            for (int kq = 0; kq < 16; kq += 2) {
                int k = k0 + kq;
                float rA = (float)r64[tok * DIM + k];
                float rB = (float)r64[tok * DIM + k + 1];
                unsigned short hA = f2bf(rA), hB = f2bf(rB);
                unsigned short lA = f2bf(rA - bf2f(hA)), lB = f2bf(rB - bf2f(hB));
                int kk = k >> 5, ls = tok + ((k >> 3) & 3) * 16, j = k & 7;
                int idx = (kk * 64 + ls) * 8 + j;          // j even -> 4B aligned
                *(unsigned*)(&abufH[idx]) = (unsigned)hA | ((unsigned)hB << 16);
                *(unsigned*)(&abufL[idx]) = (unsigned)lA | ((unsigned)lB << 16);
            }
        }
        if (tid < TPB) { dbits[tid] = 0xFFFFFFFFFFFFFFFFULL; dmin[tid] = KCB; }
        __syncthreads();

        // ---- GEMM: score* = r.c - 0.5||c||^2, 3-pass split-bf16 MFMA ----
        // wave w owns cols [w*256, w*256+256): ntiles n=0..15
        f32x4 acc[16];
        {
            const float* bl = bias + l * KCB + w * 256 + (lane & 15);
            #pragma unroll
            for (int n = 0; n < 16; n++) { float b = bl[n * 16]; acc[n] = (f32x4){b, b, b, b}; }
        }
        const short* packW = packed + (long)(l * 64 + w * 16) * 8 * 1024;
        for (int kk = 0; kk < 8; kk++) {
            bf16x8 ah = *(const bf16x8*)(abufH + kk * 512 + lane * 8);
            bf16x8 al = *(const bf16x8*)(abufL + kk * 512 + lane * 8);
            #pragma unroll
            for (int n = 0; n < 16; n++) {
                const short* pb = packW + (long)(n * 8 + kk) * 1024 + lane * 8;
                bf16x8 ch = *(const bf16x8*)pb;
                bf16x8 cl = *(const bf16x8*)(pb + 512);
                acc[n] = __builtin_amdgcn_mfma_f32_16x16x32_bf16(ah, ch, acc[n], 0, 0, 0);
                acc[n] = __builtin_amdgcn_mfma_f32_16x16x32_bf16(al, ch, acc[n], 0, 0, 0);
                acc[n] = __builtin_amdgcn_mfma_f32_16x16x32_bf16(ah, cl, acc[n], 0, 0, 0);
            }
        }

        // ---- per-token max of score* (value only; refine re-enumerates) ----
        // C/D layout: col = lane&15, row(token) = (lane>>4)*4 + reg
        float bv[4];
        #pragma unroll
        for (int r = 0; r < 4; r++) bv[r] = acc[0][r];
        #pragma unroll
        for (int n = 1; n < 16; n++)
            #pragma unroll
            for (int r = 0; r < 4; r++) bv[r] = fmaxf(bv[r], acc[n][r]);
        #pragma unroll
        for (int off = 1; off < 16; off <<= 1)
            #pragma unroll
            for (int r = 0; r < 4; r++) bv[r] = fmaxf(bv[r], __shfl_xor(bv[r], off));
        if ((lane & 15) == 0)
            #pragma unroll
            for (int r = 0; r < 4; r++) wmax[w][(lane >> 4) * 4 + r] = bv[r];
        __syncthreads();
        if (tid < TPB) {
            float m = wmax[0][tid];
            for (int ww = 1; ww < 4; ww++) m = fmaxf(m, wmax[ww][tid]);
            maxv[tid] = m;
        }
        __syncthreads();

        // ---- refine: exact f64 over candidates within margin; tie -> lowest k ----
        const float* cbl = cb + (long)l * KCB * DIM;
        #pragma unroll
        for (int n = 0; n < 16; n++)
            #pragma unroll
            for (int r = 0; r < 4; r++) {
                int tok = (lane >> 4) * 4 + r;
                if (acc[n][r] >= maxv[tok] - MARGIN_STAR) {
                    int k = w * 256 + n * 16 + (lane & 15);
                    double d = dist64(r64 + tok * DIM, cbl + (long)k * DIM);
                    atomicMin(&dbits[tok], (unsigned long long)__double_as_longlong(d));
                }
            }
        __syncthreads();
        #pragma unroll
        for (int n = 0; n < 16; n++)
            #pragma unroll
            for (int r = 0; r < 4; r++) {
                int tok = (lane >> 4) * 4 + r;
                if (acc[n][r] >= maxv[tok] - MARGIN_STAR) {
                    int k = w * 256 + n * 16 + (lane & 15);
                    double d = dist64(r64 + tok * DIM, cbl + (long)k * DIM);
                    if ((unsigned long long)__double_as_longlong(d) == dbits[tok])
                        atomicMin(&dmin[tok], k);
                }
            }
        __syncthreads();

        if (tid < TPB) codes_s[tid][l] = dmin[tid];

        // ---- residual update (f64 exact) ----
        {
            const int tok = tid >> 4, d0 = (tid & 15) * 16;
            const float* crow = cbl + (long)dmin[tok] * DIM + d0;
            for (int i = 0; i < 16; i++)
                r64[tok * DIM + d0 + i] -= (double)crow[i];
        }
        __syncthreads();
    }

    // ---- outputs ----
    {
        const int tok = tid >> 4, d0 = (tid & 15) * 16;
        for (int i = 0; i < 16; i++) {
            double q = (double)xblk[tok * DIM + d0 + i] - r64[tok * DIM + d0 + i];
            out[(tok0 + tok) * DIM + d0 + i] = (float)q;
        }
    }
    float* cout = out + (long)N_TOK * DIM;
    if (tid < TPB * LVL) {
        int t = tid >> 3, ll = tid & 7;
        cout[(tok0 + t) * LVL + ll] = (float)codes_s[t][ll];
    }
}

// ================= fallback (round-1 f32 path, needs only 32KB ws) =================
__global__ void csq_kernel(const float* __restrict__ cb, float* __restrict__ csq) {
    const int lane = threadIdx.x & 63;
    const int wid  = (blockIdx.x * blockDim.x + threadIdx.x) >> 6;
    const int nw   = (gridDim.x * blockDim.x) >> 6;
    for (int row = wid; row < LVL * KCB; row += nw) {
        float4 c = *(const float4*)(cb + (long)row * DIM + lane * 4);
        float s = c.x * c.x + c.y * c.y + c.z * c.z + c.w * c.w;
        for (int off = 32; off; off >>= 1) s += __shfl_xor(s, off);
        if (lane == 0) csq[row] = s;
    }
}

__global__ __launch_bounds__(256) void rvq_kernel(const float* __restrict__ x,
                                                  const float* __restrict__ cb,
                                                  const float* __restrict__ csq,
                                                  float* __restrict__ out) {
    __shared__ double r64[TPB * DIM];
    __shared__ float  r32[TPB * DIM];
    __shared__ float  wval[4][TPB];
    __shared__ float  minv[TPB];
    __shared__ unsigned long long dbits[TPB];
    __shared__ int    dmin_idx[TPB];
    __shared__ int    codes_s[TPB][LVL];

    const int tid  = threadIdx.x;
    const int wave = tid >> 6;
    const int lane = tid & 63;
    const long tok0 = (long)blockIdx.x * TPB;
    const float* xblk = x + tok0 * DIM;

    for (int i = 0; i < TPB; i++) {
        float v = xblk[i * DIM + tid];
        r64[i * DIM + tid] = (double)v;
        r32[i * DIM + tid] = v;
    }
    __syncthreads();

    const int k0 = wave * 256 + lane * 4;
    for (int l = 0; l < LVL; l++) {
        const float* cbl = cb + (long)l * KCB * DIM;
        float acc[4][TPB];
        #pragma unroll
        for (int j = 0; j < 4; j++)
            #pragma unroll
            for (int t = 0; t < TPB; t++) acc[j][t] = 0.f;
        for (int d0 = 0; d0 < DIM; d0 += 4) {
            float4 c4[4];
            #pragma unroll
            for (int j = 0; j < 4; j++)
                c4[j] = *(const float4*)(cbl + (long)(k0 + j) * DIM + d0);
            #pragma unroll
            for (int t = 0; t < TPB; t++) {
                float4 r4 = *(const float4*)(r32 + t * DIM + d0);
                #pragma unroll
                for (int j = 0; j < 4; j++) {
                    acc[j][t] = fmaf(c4[j].x, r4.x, acc[j][t]);
                    acc[j][t] = fmaf(c4[j].y, r4.y, acc[j][t]);
                    acc[j][t] = fmaf(c4[j].z, r4.z, acc[j][t]);
                    acc[j][t] = fmaf(c4[j].w, r4.w, acc[j][t]);
                }
            }
        }
        float cs[4];
        #pragma unroll
        for (int j = 0; j < 4; j++) cs[j] = csq[l * KCB + k0 + j];
        #pragma unroll
        for (int j = 0; j < 4; j++)
            #pragma unroll
            for (int t = 0; t < TPB; t++)
                acc[j][t] = cs[j] - 2.0f * acc[j][t];

        #pragma unroll
        for (int t = 0; t < TPB; t++) {
            float bv = acc[0][t];
            #pragma unroll
            for (int j = 1; j < 4; j++) bv = fminf(bv, acc[j][t]);
            for (int off = 1; off < 64; off <<= 1) bv = fminf(bv, __shfl_xor(bv, off));
            if (lane == 0) wval[wave][t] = bv;
        }
        __syncthreads();
        if (tid < TPB) {
            float m = wval[0][tid];
            for (int ww = 1; ww < 4; ww++) m = fminf(m, wval[ww][tid]);
            minv[tid] = m;
            dbits[tid] = 0xFFFFFFFFFFFFFFFFULL;
            dmin_idx[tid] = KCB;
        }
        __syncthreads();
        #pragma unroll
        for (int t = 0; t < TPB; t++) {
            float thr = minv[t] + MARGIN_F32;
            #pragma unroll
            for (int j = 0; j < 4; j++)
                if (acc[j][t] <= thr) {
                    double d64 = dist64(r64 + t * DIM, cbl + (long)(k0 + j) * DIM);
                    atomicMin(&dbits[t], (unsigned long long)__double_as_longlong(d64));
                }
        }
        __syncthreads();
        #pragma unroll
        for (int t = 0; t < TPB; t++) {
            float thr = minv[t] + MARGIN_F32;
            #pragma unroll
            for (int j = 0; j < 4; j++)
                if (acc[j][t] <= thr) {
                    double d64 = dist64(r64 + t * DIM, cbl + (long)(k0 + j) * DIM);
                    if ((unsigned long long)__double_as_longlong(d64) == dbits[t])
                        atomicMin(&dmin_idx[t], k0 + j);
                }
        }
        __syncthreads();
        if (tid < TPB) codes_s[tid][l] = dmin_idx[tid];
        for (int i = 0; i < TPB; i++) {
            int k = dmin_idx[i];
            float c = cbl[(long)k * DIM + tid];
            double nr = r64[i * DIM + tid] - (double)c;
            r64[i * DIM + tid] = nr;
            r32[i * DIM + tid] = (float)nr;
        }
        __syncthreads();
    }
    for (int i = 0; i < TPB; i++) {
        double q = (double)xblk[i * DIM + tid] - r64[i * DIM + tid];
        out[tok0 * DIM + i * DIM + tid] = (float)q;
    }
    float* cout = out + (long)N_TOK * DIM;
    if (tid < TPB * LVL) {
        int t = tid >> 3, ll = tid & 7;
        cout[(tok0 + t) * LVL + ll] = (float)codes_s[t][ll];
    }
}

extern "C" void kernel_launch(void* const* d_in, const int* in_sizes, int n_in,
                              void* d_out, int out_size, void* d_ws, size_t ws_size,
                              hipStream_t stream) {
    const float* x  = (const float*)d_in[0];
    const float* cb = (const float*)d_in[1];
    const size_t need = (size_t)8 * 1024 * 1024 + 32 * 1024;
    if (ws_size >= need) {
        short* packed = (short*)d_ws;
        float* bias = (float*)((char*)d_ws + (size_t)8 * 1024 * 1024);
        pack_kernel<<<1024, 256, 0, stream>>>(cb, packed);
        bias_kernel<<<32, 256, 0, stream>>>(cb, bias);
        rvq_mfma<<<N_TOK / TPB, 256, 0, stream>>>(x, cb, packed, bias, (float*)d_out);
    } else {
        float* csq = (float*)d_ws;
        csq_kernel<<<32, 256, 0, stream>>>(cb, csq);
        rvq_kernel<<<N_TOK / TPB, 256, 0, stream>>>(x, cb, csq, (float*)d_out);
    }
}

// Round 3
// 5500.807 us; speedup vs baseline: 2.3006x; 1.4741x over previous
//
#include <hip/hip_runtime.h>

#define N_TOK 65536
#define DIM   256
#define KCB   1024
#define LVL   8
#define TPB   16
#define RPAD  258                 // r64 row stride in f64 (+2 pad: bank-decorrelates rows)
#define MARGIN_STAR 0.3f          // on score* = r.c - 0.5||c||^2 ; ~15 sigma of 2-pass error
#define MARGIN_F32  0.125f        // fallback path

typedef __attribute__((ext_vector_type(8))) short bf16x8;
typedef __attribute__((ext_vector_type(4))) float f32x4;

static __device__ inline unsigned short f2bf(float f) {
    unsigned u = __float_as_uint(f);
    unsigned r = u + 0x7FFFu + ((u >> 16) & 1u);   // RNE
    return (unsigned short)(r >> 16);
}
static __device__ inline float bf2f(unsigned short h) {
    return __uint_as_float(((unsigned)h) << 16);
}

// Exact f64 ||r - c||^2. __noinline__: single code instance => bit-identical
// results at every call site (determinism of tie-breaks).
__device__ __noinline__ double dist64(const double* r, const float* crow) {
    double s0 = 0.0, s1 = 0.0, s2 = 0.0, s3 = 0.0;
    #pragma unroll 8
    for (int d = 0; d < DIM; d += 4) {
        float4 c = *(const float4*)(crow + d);
        double a = r[d]     - (double)c.x;
        double b = r[d + 1] - (double)c.y;
        double e = r[d + 2] - (double)c.z;
        double f = r[d + 3] - (double)c.w;
        s0 += a * a; s1 += b * b; s2 += e * e; s3 += f * f;
    }
    return (s0 + s1) + (s2 + s3);
}

// ---- pack: codebook -> B-fragment-linear bf16 (hi only), 1KB per frag ----
// frag f = (l*64 + n)*8 + kk ; value(lane, j) = cb[l][n*16+(lane&15)][kk*32+(lane>>4)*8+j]
__global__ void pack_kernel(const float* __restrict__ cb, short* __restrict__ packed) {
    const int lane = threadIdx.x & 63;
    const int fid  = (blockIdx.x * blockDim.x + threadIdx.x) >> 6;  // 0..4095
    const int l  = fid >> 9;
    const int n  = (fid >> 3) & 63;
    const int kk = fid & 7;
    const int col = n * 16 + (lane & 15);
    const int kb  = kk * 32 + (lane >> 4) * 8;
    const float* src = cb + ((long)(l * KCB + col)) * DIM + kb;
    float4 f0 = *(const float4*)src;
    float4 f1 = *(const float4*)(src + 4);
    float fv[8] = {f0.x, f0.y, f0.z, f0.w, f1.x, f1.y, f1.z, f1.w};
    union { unsigned short s[8]; int4 v; } H;
    #pragma unroll
    for (int j = 0; j < 8; j++) H.s[j] = f2bf(fv[j]);
    *(int4*)(packed + (long)fid * 512 + lane * 8) = H.v;
}

// bias[l*K + k] = -0.5 * ||cb[l][k]||^2
__global__ void bias_kernel(const float* __restrict__ cb, float* __restrict__ bias) {
    const int lane = threadIdx.x & 63;
    const int wid  = (blockIdx.x * blockDim.x + threadIdx.x) >> 6;
    const int nw   = (gridDim.x * blockDim.x) >> 6;
    for (int row = wid; row < LVL * KCB; row += nw) {
        float4 c = *(const float4*)(cb + (long)row * DIM + lane * 4);
        float s = c.x * c.x + c.y * c.y + c.z * c.z + c.w * c.w;
        for (int off = 32; off; off >>= 1) s += __shfl_xor(s, off);
        if (lane == 0) bias[row] = -0.5f * s;
    }
}

// ---------------- main ----------------
__global__ __launch_bounds__(256, 3) void rvq_mfma(const float* __restrict__ x,
                                                   const float* __restrict__ cb,
                                                   const short* __restrict__ packed,
                                                   const float* __restrict__ bias,
                                                   float* __restrict__ out) {
    __shared__ double r64[TPB * RPAD];      // 33024 B, padded rows
    __shared__ short  abufH[8 * 64 * 8];    // 8 KB A-frags hi
    __shared__ short  abufL[8 * 64 * 8];    // 8 KB A-frags lo
    __shared__ float  wmax[4][TPB];
    __shared__ double wbd[4][TPB];
    __shared__ int    wbk[4][TPB];
    __shared__ int    codes_s[TPB][LVL];

    const int tid  = threadIdx.x;
    const int w    = tid >> 6;
    const int lane = tid & 63;
    const int tokq = tid >> 4;      // token this thread serves in convert/update
    const int c16  = tid & 15;
    const long tok0 = (long)blockIdx.x * TPB;
    const float* xblk = x + tok0 * DIM;

    // init residual: lane-contiguous (conflict-free) + coalesced global
    #pragma unroll
    for (int i = 0; i < 16; i++) {
        int d = c16 + 16 * i;
        r64[tokq * RPAD + d] = (double)xblk[tokq * DIM + d];
    }
    __syncthreads();

    for (int l = 0; l < LVL; l++) {
        const float* cbl = cb + (long)l * KCB * DIM;

        // ---- A-convert: r64 -> bf16 hi/lo fragments (pairs => 4B writes) ----
        #pragma unroll
        for (int i = 0; i < 8; i++) {
            int d = 2 * c16 + 32 * i;                       // kk = i
            double rA = r64[tokq * RPAD + d];
            double rB = r64[tokq * RPAD + d + 1];
            float fA = (float)rA, fB = (float)rB;
            unsigned short hA = f2bf(fA), hB = f2bf(fB);
            unsigned short lA = f2bf(fA - bf2f(hA)), lB = f2bf(fB - bf2f(hB));
            int ls  = tokq + (((2 * c16) >> 3) & 3) * 16;
            int idx = (i * 64 + ls) * 8 + ((2 * c16) & 7);  // even j -> 4B aligned
            *(unsigned*)&abufH[idx] = (unsigned)hA | ((unsigned)hB << 16);
            *(unsigned*)&abufL[idx] = (unsigned)lA | ((unsigned)lB << 16);
        }
        __syncthreads();

        // ---- GEMM: score* = r.c - 0.5||c||^2 ; 2-pass split-bf16 (hi-only B) ----
        f32x4 acc[16];
        {
            const float* bl = bias + l * KCB + w * 256 + (lane & 15);
            #pragma unroll
            for (int n = 0; n < 16; n++) { float b = bl[n * 16]; acc[n] = (f32x4){b, b, b, b}; }
        }
        const short* packW = packed + (long)(l * 64 + w * 16) * 8 * 512;
        for (int kk = 0; kk < 8; kk++) {
            bf16x8 ah = *(const bf16x8*)(abufH + kk * 512 + lane * 8);
            bf16x8 al = *(const bf16x8*)(abufL + kk * 512 + lane * 8);
            #pragma unroll
            for (int n = 0; n < 16; n++) {
                bf16x8 ch = *(const bf16x8*)(packW + (long)(n * 8 + kk) * 512 + lane * 8);
                acc[n] = __builtin_amdgcn_mfma_f32_16x16x32_bf16(ah, ch, acc[n], 0, 0, 0);
                acc[n] = __builtin_amdgcn_mfma_f32_16x16x32_bf16(al, ch, acc[n], 0, 0, 0);
            }
        }

        // ---- per-token max (C/D: col=lane&15, tok=(lane>>4)*4+reg) ----
        float bv[4];
        #pragma unroll
        for (int r = 0; r < 4; r++) bv[r] = acc[0][r];
        #pragma unroll
        for (int n = 1; n < 16; n++)
            #pragma unroll
            for (int r = 0; r < 4; r++) bv[r] = fmaxf(bv[r], acc[n][r]);
        #pragma unroll
        for (int off = 1; off < 16; off <<= 1)
            #pragma unroll
            for (int r = 0; r < 4; r++) bv[r] = fmaxf(bv[r], __shfl_xor(bv[r], off));
        if ((lane & 15) == 0)
            #pragma unroll
            for (int r = 0; r < 4; r++) wmax[w][(lane >> 4) * 4 + r] = bv[r];
        __syncthreads();

        // ---- refine: single pass, per-lane best (d64, k), shuffle reduce ----
        double bd[4]; int bk[4]; float mv[4];
        #pragma unroll
        for (int r = 0; r < 4; r++) {
            int tokr = (lane >> 4) * 4 + r;
            float m = wmax[0][tokr];
            #pragma unroll
            for (int ww = 1; ww < 4; ww++) m = fmaxf(m, wmax[ww][tokr]);
            mv[r] = m - MARGIN_STAR;
            bd[r] = 1e300; bk[r] = KCB;
        }
        #pragma unroll
        for (int n = 0; n < 16; n++)
            #pragma unroll
            for (int r = 0; r < 4; r++) {
                if (acc[n][r] >= mv[r]) {
                    int tokr = (lane >> 4) * 4 + r;
                    int k = w * 256 + n * 16 + (lane & 15);
                    double d = dist64(r64 + tokr * RPAD, cbl + (long)k * DIM);
                    if (d < bd[r]) { bd[r] = d; bk[r] = k; }
                }
            }
        #pragma unroll
        for (int off = 1; off < 16; off <<= 1)
            #pragma unroll
            for (int r = 0; r < 4; r++) {
                double od = __shfl_xor(bd[r], off);
                int    ok = __shfl_xor(bk[r], off);
                if (od < bd[r] || (od == bd[r] && ok < bk[r])) { bd[r] = od; bk[r] = ok; }
            }
        if ((lane & 15) == 0)
            #pragma unroll
            for (int r = 0; r < 4; r++) {
                wbd[w][(lane >> 4) * 4 + r] = bd[r];
                wbk[w][(lane >> 4) * 4 + r] = bk[r];
            }
        __syncthreads();

        // ---- final reduce (redundant per-thread, deterministic) + update ----
        {
            double fb = wbd[0][tokq]; int fk = wbk[0][tokq];
            #pragma unroll
            for (int ww = 1; ww < 4; ww++) {
                double od = wbd[ww][tokq]; int ok = wbk[ww][tokq];
                if (od < fb || (od == fb && ok < fk)) { fb = od; fk = ok; }
            }
            if (c16 == 0) codes_s[tokq][l] = fk;
            const float* crow = cbl + (long)fk * DIM;
            #pragma unroll
            for (int i = 0; i < 16; i++) {
                int d = c16 + 16 * i;
                r64[tokq * RPAD + d] -= (double)crow[d];
            }
        }
        __syncthreads();
    }

    // ---- outputs: quantized = x - residual ; codes as float ----
    #pragma unroll
    for (int i = 0; i < 16; i++) {
        int d = c16 + 16 * i;
        double q = (double)xblk[tokq * DIM + d] - r64[tokq * RPAD + d];
        out[(tok0 + tokq) * DIM + d] = (float)q;
    }
    float* cout = out + (long)N_TOK * DIM;
    if (tid < TPB * LVL) {
        int t = tid >> 3, ll = tid & 7;
        cout[(tok0 + t) * LVL + ll] = (float)codes_s[t][ll];
    }
}

// ================= fallback (f32 path, needs only 32KB ws) =================
__global__ void csq_kernel(const float* __restrict__ cb, float* __restrict__ csq) {
    const int lane = threadIdx.x & 63;
    const int wid  = (blockIdx.x * blockDim.x + threadIdx.x) >> 6;
    const int nw   = (gridDim.x * blockDim.x) >> 6;
    for (int row = wid; row < LVL * KCB; row += nw) {
        float4 c = *(const float4*)(cb + (long)row * DIM + lane * 4);
        float s = c.x * c.x + c.y * c.y + c.z * c.z + c.w * c.w;
        for (int off = 32; off; off >>= 1) s += __shfl_xor(s, off);
        if (lane == 0) csq[row] = s;
    }
}

__global__ __launch_bounds__(256) void rvq_kernel(const float* __restrict__ x,
                                                  const float* __restrict__ cb,
                                                  const float* __restrict__ csq,
                                                  float* __restrict__ out) {
    __shared__ double r64[TPB * RPAD];
    __shared__ float  r32[TPB * DIM];
    __shared__ float  wval[4][TPB];
    __shared__ float  minv[TPB];
    __shared__ unsigned long long dbits[TPB];
    __shared__ int    dmin_idx[TPB];
    __shared__ int    codes_s[TPB][LVL];

    const int tid  = threadIdx.x;
    const int wave = tid >> 6;
    const int lane = tid & 63;
    const long tok0 = (long)blockIdx.x * TPB;
    const float* xblk = x + tok0 * DIM;

    for (int i = 0; i < TPB; i++) {
        float v = xblk[i * DIM + tid];
        r64[i * RPAD + tid] = (double)v;
        r32[i * DIM + tid] = v;
    }
    __syncthreads();

    const int k0 = wave * 256 + lane * 4;
    for (int l = 0; l < LVL; l++) {
        const float* cbl = cb + (long)l * KCB * DIM;
        float acc[4][TPB];
        #pragma unroll
        for (int j = 0; j < 4; j++)
            #pragma unroll
            for (int t = 0; t < TPB; t++) acc[j][t] = 0.f;
        for (int d0 = 0; d0 < DIM; d0 += 4) {
            float4 c4[4];
            #pragma unroll
            for (int j = 0; j < 4; j++)
                c4[j] = *(const float4*)(cbl + (long)(k0 + j) * DIM + d0);
            #pragma unroll
            for (int t = 0; t < TPB; t++) {
                float4 r4 = *(const float4*)(r32 + t * DIM + d0);
                #pragma unroll
                for (int j = 0; j < 4; j++) {
                    acc[j][t] = fmaf(c4[j].x, r4.x, acc[j][t]);
                    acc[j][t] = fmaf(c4[j].y, r4.y, acc[j][t]);
                    acc[j][t] = fmaf(c4[j].z, r4.z, acc[j][t]);
                    acc[j][t] = fmaf(c4[j].w, r4.w, acc[j][t]);
                }
            }
        }
        float cs[4];
        #pragma unroll
        for (int j = 0; j < 4; j++) cs[j] = csq[l * KCB + k0 + j];
        #pragma unroll
        for (int j = 0; j < 4; j++)
            #pragma unroll
            for (int t = 0; t < TPB; t++)
                acc[j][t] = cs[j] - 2.0f * acc[j][t];

        #pragma unroll
        for (int t = 0; t < TPB; t++) {
            float bv = acc[0][t];
            #pragma unroll
            for (int j = 1; j < 4; j++) bv = fminf(bv, acc[j][t]);
            for (int off = 1; off < 64; off <<= 1) bv = fminf(bv, __shfl_xor(bv, off));
            if (lane == 0) wval[wave][t] = bv;
        }
        __syncthreads();
        if (tid < TPB) {
            float m = wval[0][tid];
            for (int ww = 1; ww < 4; ww++) m = fminf(m, wval[ww][tid]);
            minv[tid] = m;
            dbits[tid] = 0xFFFFFFFFFFFFFFFFULL;
            dmin_idx[tid] = KCB;
        }
        __syncthreads();
        #pragma unroll
        for (int t = 0; t < TPB; t++) {
            float thr = minv[t] + MARGIN_F32;
            #pragma unroll
            for (int j = 0; j < 4; j++)
                if (acc[j][t] <= thr) {
                    double d64 = dist64(r64 + t * RPAD, cbl + (long)(k0 + j) * DIM);
                    atomicMin(&dbits[t], (unsigned long long)__double_as_longlong(d64));
                }
        }
        __syncthreads();
        #pragma unroll
        for (int t = 0; t < TPB; t++) {
            float thr = minv[t] + MARGIN_F32;
            #pragma unroll
            for (int j = 0; j < 4; j++)
                if (acc[j][t] <= thr) {
                    double d64 = dist64(r64 + t * RPAD, cbl + (long)(k0 + j) * DIM);
                    if ((unsigned long long)__double_as_longlong(d64) == dbits[t])
                        atomicMin(&dmin_idx[t], k0 + j);
                }
        }
        __syncthreads();
        if (tid < TPB) codes_s[tid][l] = dmin_idx[tid];
        for (int i = 0; i < TPB; i++) {
            int k = dmin_idx[i];
            float c = cbl[(long)k * DIM + tid];
            double nr = r64[i * RPAD + tid] - (double)c;
            r64[i * RPAD + tid] = nr;
            r32[i * DIM + tid] = (float)nr;
        }
        __syncthreads();
    }
    for (int i = 0; i < TPB; i++) {
        double q = (double)xblk[i * DIM + tid] - r64[i * RPAD + tid];
        out[tok0 * DIM + i * DIM + tid] = (float)q;
    }
    float* cout = out + (long)N_TOK * DIM;
    if (tid < TPB * LVL) {
        int t = tid >> 3, ll = tid & 7;
        cout[(tok0 + t) * LVL + ll] = (float)codes_s[t][ll];
    }
}

extern "C" void kernel_launch(void* const* d_in, const int* in_sizes, int n_in,
                              void* d_out, int out_size, void* d_ws, size_t ws_size,
                              hipStream_t stream) {
    const float* x  = (const float*)d_in[0];
    const float* cb = (const float*)d_in[1];
    const size_t need = (size_t)4 * 1024 * 1024 + 32 * 1024;
    if (ws_size >= need) {
        short* packed = (short*)d_ws;
        float* bias = (float*)((char*)d_ws + (size_t)4 * 1024 * 1024);
        pack_kernel<<<1024, 256, 0, stream>>>(cb, packed);
        bias_kernel<<<32, 256, 0, stream>>>(cb, bias);
        rvq_mfma<<<N_TOK / TPB, 256, 0, stream>>>(x, cb, packed, bias, (float*)d_out);
    } else {
        float* csq = (float*)d_ws;
        csq_kernel<<<32, 256, 0, stream>>>(cb, csq);
        rvq_kernel<<<N_TOK / TPB, 256, 0, stream>>>(x, cb, csq, (float*)d_out);
    }
}

// Round 4
// 1194.275 us; speedup vs baseline: 10.5966x; 4.6060x over previous
//
#include <hip/hip_runtime.h>

#define N_TOK 65536
#define DIM   256
#define KCB   1024
#define LVL   8
#define TPB   16                  // tokens per block
#define THREADS 512               // 8 waves
#define CAND_MAX 32
#define MARGIN_STAR 0.3f          // on score* = r.c - 0.5||c||^2 (same as R3)
#define MARGIN_F32  0.125f        // fallback path
#define RPAD  258                 // fallback r64 row stride

typedef __attribute__((ext_vector_type(8))) short bf16x8;
typedef __attribute__((ext_vector_type(4))) float f32x4;

static __device__ inline unsigned short f2bf(float f) {
    unsigned u = __float_as_uint(f);
    unsigned r = u + 0x7FFFu + ((u >> 16) & 1u);   // RNE
    return (unsigned short)(r >> 16);
}
static __device__ inline float bf2f(unsigned short h) {
    return __uint_as_float(((unsigned)h) << 16);
}

// Exact f64 ||r - c||^2 (fallback path only). __noinline__: single instance.
__device__ __noinline__ double dist64(const double* r, const float* crow) {
    double s0 = 0.0, s1 = 0.0, s2 = 0.0, s3 = 0.0;
    #pragma unroll 8
    for (int d = 0; d < DIM; d += 4) {
        float4 c = *(const float4*)(crow + d);
        double a = r[d]     - (double)c.x;
        double b = r[d + 1] - (double)c.y;
        double e = r[d + 2] - (double)c.z;
        double f = r[d + 3] - (double)c.w;
        s0 += a * a; s1 += b * b; s2 += e * e; s3 += f * f;
    }
    return (s0 + s1) + (s2 + s3);
}

// ---- pack: codebook -> B-fragment-linear bf16 (hi only), 1KB per frag ----
// frag f = (l*64 + N)*8 + kk ; value(lane, j) = cb[l][N*16+(lane&15)][kk*32+(lane>>4)*8+j]
__global__ void pack_kernel(const float* __restrict__ cb, short* __restrict__ packed) {
    const int lane = threadIdx.x & 63;
    const int fid  = (blockIdx.x * blockDim.x + threadIdx.x) >> 6;  // 0..4095
    const int l  = fid >> 9;
    const int n  = (fid >> 3) & 63;
    const int kk = fid & 7;
    const int col = n * 16 + (lane & 15);
    const int kb  = kk * 32 + (lane >> 4) * 8;
    const float* src = cb + ((long)(l * KCB + col)) * DIM + kb;
    float4 f0 = *(const float4*)src;
    float4 f1 = *(const float4*)(src + 4);
    float fv[8] = {f0.x, f0.y, f0.z, f0.w, f1.x, f1.y, f1.z, f1.w};
    union { unsigned short s[8]; int4 v; } H;
    #pragma unroll
    for (int j = 0; j < 8; j++) H.s[j] = f2bf(fv[j]);
    *(int4*)(packed + (long)fid * 512 + lane * 8) = H.v;
}

// bias[l*K + k] = -0.5 * ||cb[l][k]||^2
__global__ void bias_kernel(const float* __restrict__ cb, float* __restrict__ bias) {
    const int lane = threadIdx.x & 63;
    const int wid  = (blockIdx.x * blockDim.x + threadIdx.x) >> 6;
    const int nw   = (gridDim.x * blockDim.x) >> 6;
    for (int row = wid; row < LVL * KCB; row += nw) {
        float4 c = *(const float4*)(cb + (long)row * DIM + lane * 4);
        float s = c.x * c.x + c.y * c.y + c.z * c.z + c.w * c.w;
        for (int off = 32; off; off >>= 1) s += __shfl_xor(s, off);
        if (lane == 0) bias[row] = -0.5f * s;
    }
}

// ---------------- main: 8-wave, residual-in-registers ----------------
__global__ __launch_bounds__(THREADS, 4) void rvq_mfma(const float* __restrict__ x,
                                                       const float* __restrict__ cb,
                                                       const short* __restrict__ packed,
                                                       const float* __restrict__ bias,
                                                       float* __restrict__ out) {
    __shared__ short abufH[8 * 64 * 8];    // 8 KB A-frags hi
    __shared__ short abufL[8 * 64 * 8];    // 8 KB A-frags lo
    __shared__ float bias_s[KCB];          // 4 KB per-level bias
    __shared__ float wmax[8][TPB];
    __shared__ int   ccnt[TPB];
    __shared__ int   clist[TPB][CAND_MAX];
    __shared__ int   codes_s[TPB][LVL];

    const int tid  = threadIdx.x;
    const int w    = tid >> 6;            // wave 0..7 -> cols [w*128, w*128+128)
    const int lane = tid & 63;
    const int tokq = tid >> 5;            // token 0..15 (32-thread group)
    const int c32  = tid & 31;
    const long tok0 = (long)blockIdx.x * TPB;
    const float* xblk = x + tok0 * DIM;

    // residual in registers: dims d = 2*c32 + 64*p + {0,1}, p = 0..3
    double res[8];
    #pragma unroll
    for (int p = 0; p < 4; p++) {
        float2 xv = *(const float2*)(xblk + tokq * DIM + 2 * c32 + 64 * p);
        res[2 * p]     = (double)xv.x;
        res[2 * p + 1] = (double)xv.y;
    }

    for (int l = 0; l < LVL; l++) {
        const float* cbl = cb + (long)l * KCB * DIM;

        // ---- phase 1: A-convert (regs -> bf16 hi/lo frags) + bias stage + reset ----
        #pragma unroll
        for (int p = 0; p < 4; p++) {
            int d = 2 * c32 + 64 * p;
            float fA = (float)res[2 * p], fB = (float)res[2 * p + 1];
            unsigned short hA = f2bf(fA), hB = f2bf(fB);
            unsigned short lA = f2bf(fA - bf2f(hA)), lB = f2bf(fB - bf2f(hB));
            int kk  = d >> 5;
            int ls  = tokq + ((d >> 3) & 3) * 16;
            int idx = (kk * 64 + ls) * 8 + (d & 7);         // even -> 4B aligned
            *(unsigned*)&abufH[idx] = (unsigned)hA | ((unsigned)hB << 16);
            *(unsigned*)&abufL[idx] = (unsigned)lA | ((unsigned)lB << 16);
        }
        bias_s[tid]           = bias[l * KCB + tid];
        bias_s[tid + THREADS] = bias[l * KCB + tid + THREADS];
        if (tid < TPB) ccnt[tid] = 0;
        __syncthreads();

        // ---- phase 2: GEMM score* = r.c - 0.5||c||^2 (2-pass split-bf16) ----
        f32x4 acc[8];
        #pragma unroll
        for (int n = 0; n < 8; n++) {
            float b = bias_s[w * 128 + n * 16 + (lane & 15)];
            acc[n] = (f32x4){b, b, b, b};
        }
        const short* packW = packed + ((long)(l * 64 + w * 8) * 8) * 512 + lane * 8;
        for (int kk = 0; kk < 8; kk++) {
            bf16x8 ah = *(const bf16x8*)(abufH + kk * 512 + lane * 8);
            bf16x8 al = *(const bf16x8*)(abufL + kk * 512 + lane * 8);
            bf16x8 chv[8];
            #pragma unroll
            for (int n = 0; n < 8; n++)
                chv[n] = *(const bf16x8*)(packW + (long)(n * 8 + kk) * 512);
            #pragma unroll
            for (int n = 0; n < 8; n++) {
                acc[n] = __builtin_amdgcn_mfma_f32_16x16x32_bf16(ah, chv[n], acc[n], 0, 0, 0);
                acc[n] = __builtin_amdgcn_mfma_f32_16x16x32_bf16(al, chv[n], acc[n], 0, 0, 0);
            }
        }

        // ---- wave-level per-token max (C/D: col=lane&15, tok=(lane>>4)*4+r) ----
        float bv[4];
        #pragma unroll
        for (int r = 0; r < 4; r++) bv[r] = acc[0][r];
        #pragma unroll
        for (int n = 1; n < 8; n++)
            #pragma unroll
            for (int r = 0; r < 4; r++) bv[r] = fmaxf(bv[r], acc[n][r]);
        #pragma unroll
        for (int off = 1; off < 16; off <<= 1)
            #pragma unroll
            for (int r = 0; r < 4; r++) bv[r] = fmaxf(bv[r], __shfl_xor(bv[r], off));
        if ((lane & 15) == 0)
            #pragma unroll
            for (int r = 0; r < 4; r++) wmax[w][(lane >> 4) * 4 + r] = bv[r];
        __syncthreads();

        // ---- phase 3: candidate scan -> per-token LDS lists ----
        #pragma unroll
        for (int r = 0; r < 4; r++) {
            int tok = (lane >> 4) * 4 + r;
            float m = wmax[0][tok];
            #pragma unroll
            for (int ww = 1; ww < 8; ww++) m = fmaxf(m, wmax[ww][tok]);
            float thr = m - MARGIN_STAR;
            #pragma unroll
            for (int n = 0; n < 8; n++) {
                if (acc[n][r] >= thr) {
                    int k = w * 128 + n * 16 + (lane & 15);
                    int pos = atomicAdd(&ccnt[tok], 1);
                    if (pos < CAND_MAX) clist[tok][pos] = k;
                }
            }
        }
        __syncthreads();

        // ---- phase 4: cooperative exact-f64 refine (32 threads/token) + update ----
        int cnt = ccnt[tokq];
        if (cnt > CAND_MAX) cnt = CAND_MAX;
        double bd = 1e300; int bk = KCB;
        for (int j = 0; j < cnt; j++) {
            int k = clist[tokq][j];
            const float* crow = cbl + (long)k * DIM + 2 * c32;
            double s = 0.0;
            #pragma unroll
            for (int p = 0; p < 4; p++) {
                float2 cv = *(const float2*)(crow + 64 * p);
                double a  = res[2 * p]     - (double)cv.x;
                double b2 = res[2 * p + 1] - (double)cv.y;
                s += a * a + b2 * b2;
            }
            #pragma unroll
            for (int off = 1; off < 32; off <<= 1) s += __shfl_xor(s, off);
            if (s < bd || (s == bd && k < bk)) { bd = s; bk = k; }
        }
        if (c32 == 0) codes_s[tokq][l] = bk;
        {
            const float* crow = cbl + (long)bk * DIM + 2 * c32;
            #pragma unroll
            for (int p = 0; p < 4; p++) {
                float2 cv = *(const float2*)(crow + 64 * p);
                res[2 * p]     -= (double)cv.x;
                res[2 * p + 1] -= (double)cv.y;
            }
        }
        __syncthreads();
    }

    // ---- outputs: quantized = x - residual ; codes as float ----
    #pragma unroll
    for (int p = 0; p < 4; p++) {
        int d = 2 * c32 + 64 * p;
        float2 xv = *(const float2*)(xblk + tokq * DIM + d);
        float2 q;
        q.x = (float)((double)xv.x - res[2 * p]);
        q.y = (float)((double)xv.y - res[2 * p + 1]);
        *(float2*)(out + (tok0 + tokq) * DIM + d) = q;
    }
    float* cout = out + (long)N_TOK * DIM;
    if (tid < TPB * LVL) {
        int t = tid >> 3, ll = tid & 7;
        cout[(tok0 + t) * LVL + ll] = (float)codes_s[t][ll];
    }
}

// ================= fallback (f32 path, needs only 32KB ws) =================
__global__ void csq_kernel(const float* __restrict__ cb, float* __restrict__ csq) {
    const int lane = threadIdx.x & 63;
    const int wid  = (blockIdx.x * blockDim.x + threadIdx.x) >> 6;
    const int nw   = (gridDim.x * blockDim.x) >> 6;
    for (int row = wid; row < LVL * KCB; row += nw) {
        float4 c = *(const float4*)(cb + (long)row * DIM + lane * 4);
        float s = c.x * c.x + c.y * c.y + c.z * c.z + c.w * c.w;
        for (int off = 32; off; off >>= 1) s += __shfl_xor(s, off);
        if (lane == 0) csq[row] = s;
    }
}

__global__ __launch_bounds__(256) void rvq_kernel(const float* __restrict__ x,
                                                  const float* __restrict__ cb,
                                                  const float* __restrict__ csq,
                                                  float* __restrict__ out) {
    __shared__ double r64[TPB * RPAD];
    __shared__ float  r32[TPB * DIM];
    __shared__ float  wval[4][TPB];
    __shared__ float  minv[TPB];
    __shared__ unsigned long long dbits[TPB];
    __shared__ int    dmin_idx[TPB];
    __shared__ int    codes_s[TPB][LVL];

    const int tid  = threadIdx.x;
    const int wave = tid >> 6;
    const int lane = tid & 63;
    const long tok0 = (long)blockIdx.x * TPB;
    const float* xblk = x + tok0 * DIM;

    for (int i = 0; i < TPB; i++) {
        float v = xblk[i * DIM + tid];
        r64[i * RPAD + tid] = (double)v;
        r32[i * DIM + tid] = v;
    }
    __syncthreads();

    const int k0 = wave * 256 + lane * 4;
    for (int l = 0; l < LVL; l++) {
        const float* cbl = cb + (long)l * KCB * DIM;
        float acc[4][TPB];
        #pragma unroll
        for (int j = 0; j < 4; j++)
            #pragma unroll
            for (int t = 0; t < TPB; t++) acc[j][t] = 0.f;
        for (int d0 = 0; d0 < DIM; d0 += 4) {
            float4 c4[4];
            #pragma unroll
            for (int j = 0; j < 4; j++)
                c4[j] = *(const float4*)(cbl + (long)(k0 + j) * DIM + d0);
            #pragma unroll
            for (int t = 0; t < TPB; t++) {
                float4 r4 = *(const float4*)(r32 + t * DIM + d0);
                #pragma unroll
                for (int j = 0; j < 4; j++) {
                    acc[j][t] = fmaf(c4[j].x, r4.x, acc[j][t]);
                    acc[j][t] = fmaf(c4[j].y, r4.y, acc[j][t]);
                    acc[j][t] = fmaf(c4[j].z, r4.z, acc[j][t]);
                    acc[j][t] = fmaf(c4[j].w, r4.w, acc[j][t]);
                }
            }
        }
        float cs[4];
        #pragma unroll
        for (int j = 0; j < 4; j++) cs[j] = csq[l * KCB + k0 + j];
        #pragma unroll
        for (int j = 0; j < 4; j++)
            #pragma unroll
            for (int t = 0; t < TPB; t++)
                acc[j][t] = cs[j] - 2.0f * acc[j][t];

        #pragma unroll
        for (int t = 0; t < TPB; t++) {
            float bv = acc[0][t];
            #pragma unroll
            for (int j = 1; j < 4; j++) bv = fminf(bv, acc[j][t]);
            for (int off = 1; off < 64; off <<= 1) bv = fminf(bv, __shfl_xor(bv, off));
            if (lane == 0) wval[wave][t] = bv;
        }
        __syncthreads();
        if (tid < TPB) {
            float m = wval[0][tid];
            for (int ww = 1; ww < 4; ww++) m = fminf(m, wval[ww][tid]);
            minv[tid] = m;
            dbits[tid] = 0xFFFFFFFFFFFFFFFFULL;
            dmin_idx[tid] = KCB;
        }
        __syncthreads();
        #pragma unroll
        for (int t = 0; t < TPB; t++) {
            float thr = minv[t] + MARGIN_F32;
            #pragma unroll
            for (int j = 0; j < 4; j++)
                if (acc[j][t] <= thr) {
                    double d64 = dist64(r64 + t * RPAD, cbl + (long)(k0 + j) * DIM);
                    atomicMin(&dbits[t], (unsigned long long)__double_as_longlong(d64));
                }
        }
        __syncthreads();
        #pragma unroll
        for (int t = 0; t < TPB; t++) {
            float thr = minv[t] + MARGIN_F32;
            #pragma unroll
            for (int j = 0; j < 4; j++)
                if (acc[j][t] <= thr) {
                    double d64 = dist64(r64 + t * RPAD, cbl + (long)(k0 + j) * DIM);
                    if ((unsigned long long)__double_as_longlong(d64) == dbits[t])
                        atomicMin(&dmin_idx[t], k0 + j);
                }
        }
        __syncthreads();
        if (tid < TPB) codes_s[tid][l] = dmin_idx[tid];
        for (int i = 0; i < TPB; i++) {
            int k = dmin_idx[i];
            float c = cbl[(long)k * DIM + tid];
            double nr = r64[i * RPAD + tid] - (double)c;
            r64[i * RPAD + tid] = nr;
            r32[i * DIM + tid] = (float)nr;
        }
        __syncthreads();
    }
    for (int i = 0; i < TPB; i++) {
        double q = (double)xblk[i * DIM + tid] - r64[i * RPAD + tid];
        out[tok0 * DIM + i * DIM + tid] = (float)q;
    }
    float* cout = out + (long)N_TOK * DIM;
    if (tid < TPB * LVL) {
        int t = tid >> 3, ll = tid & 7;
        cout[(tok0 + t) * LVL + ll] = (float)codes_s[t][ll];
    }
}

extern "C" void kernel_launch(void* const* d_in, const int* in_sizes, int n_in,
                              void* d_out, int out_size, void* d_ws, size_t ws_size,
                              hipStream_t stream) {
    const float* x  = (const float*)d_in[0];
    const float* cb = (const float*)d_in[1];
    const size_t need = (size_t)4 * 1024 * 1024 + 32 * 1024;
    if (ws_size >= need) {
        short* packed = (short*)d_ws;
        float* bias = (float*)((char*)d_ws + (size_t)4 * 1024 * 1024);
        pack_kernel<<<1024, 256, 0, stream>>>(cb, packed);
        bias_kernel<<<32, 256, 0, stream>>>(cb, bias);
        rvq_mfma<<<N_TOK / TPB, THREADS, 0, stream>>>(x, cb, packed, bias, (float*)d_out);
    } else {
        float* csq = (float*)d_ws;
        csq_kernel<<<32, 256, 0, stream>>>(cb, csq);
        rvq_kernel<<<N_TOK / TPB, 256, 0, stream>>>(x, cb, csq, (float*)d_out);
    }
}

// Round 5
// 842.746 us; speedup vs baseline: 15.0166x; 1.4171x over previous
//
#include <hip/hip_runtime.h>

#define N_TOK 65536
#define DIM   256
#define KCB   1024
#define LVL   8
#define TPB   32                  // tokens per block
#define THREADS 1024              // 16 waves
#define CAND_MAX 32
#define MARGIN_STAR 0.3f          // on score* = r.c - 0.5||c||^2 (same as R3/R4)
#define MARGIN_F32  0.125f        // fallback path
#define RPAD  258                 // fallback r64 row stride

typedef __attribute__((ext_vector_type(8))) short bf16x8;
typedef __attribute__((ext_vector_type(4))) float f32x4;

static __device__ inline unsigned short f2bf(float f) {
    unsigned u = __float_as_uint(f);
    unsigned r = u + 0x7FFFu + ((u >> 16) & 1u);   // RNE
    return (unsigned short)(r >> 16);
}
static __device__ inline float bf2f(unsigned short h) {
    return __uint_as_float(((unsigned)h) << 16);
}

// Exact f64 ||r - c||^2 (fallback path only). __noinline__: single instance.
__device__ __noinline__ double dist64(const double* r, const float* crow) {
    double s0 = 0.0, s1 = 0.0, s2 = 0.0, s3 = 0.0;
    #pragma unroll 8
    for (int d = 0; d < DIM; d += 4) {
        float4 c = *(const float4*)(crow + d);
        double a = r[d]     - (double)c.x;
        double b = r[d + 1] - (double)c.y;
        double e = r[d + 2] - (double)c.z;
        double f = r[d + 3] - (double)c.w;
        s0 += a * a; s1 += b * b; s2 += e * e; s3 += f * f;
    }
    return (s0 + s1) + (s2 + s3);
}

// ---- pack: codebook -> B-fragment-linear bf16 (hi only), 1KB per frag ----
// frag f = (l*64 + N)*8 + kk ; value(lane, j) = cb[l][N*16+(lane&15)][kk*32+(lane>>4)*8+j]
__global__ void pack_kernel(const float* __restrict__ cb, short* __restrict__ packed) {
    const int lane = threadIdx.x & 63;
    const int fid  = (blockIdx.x * blockDim.x + threadIdx.x) >> 6;  // 0..4095
    const int l  = fid >> 9;
    const int n  = (fid >> 3) & 63;
    const int kk = fid & 7;
    const int col = n * 16 + (lane & 15);
    const int kb  = kk * 32 + (lane >> 4) * 8;
    const float* src = cb + ((long)(l * KCB + col)) * DIM + kb;
    float4 f0 = *(const float4*)src;
    float4 f1 = *(const float4*)(src + 4);
    float fv[8] = {f0.x, f0.y, f0.z, f0.w, f1.x, f1.y, f1.z, f1.w};
    union { unsigned short s[8]; int4 v; } H;
    #pragma unroll
    for (int j = 0; j < 8; j++) H.s[j] = f2bf(fv[j]);
    *(int4*)(packed + (long)fid * 512 + lane * 8) = H.v;
}

// bias[l*K + k] = -0.5 * ||cb[l][k]||^2
__global__ void bias_kernel(const float* __restrict__ cb, float* __restrict__ bias) {
    const int lane = threadIdx.x & 63;
    const int wid  = (blockIdx.x * blockDim.x + threadIdx.x) >> 6;
    const int nw   = (gridDim.x * blockDim.x) >> 6;
    for (int row = wid; row < LVL * KCB; row += nw) {
        float4 c = *(const float4*)(cb + (long)row * DIM + lane * 4);
        float s = c.x * c.x + c.y * c.y + c.z * c.z + c.w * c.w;
        for (int off = 32; off; off >>= 1) s += __shfl_xor(s, off);
        if (lane == 0) bias[row] = -0.5f * s;
    }
}

// ---------------- main: 16-wave, 32-token tile, residual-in-registers ----------------
__global__ __launch_bounds__(THREADS, 4) void rvq_mfma(const float* __restrict__ x,
                                                       const float* __restrict__ cb,
                                                       const short* __restrict__ packed,
                                                       const float* __restrict__ bias,
                                                       float* __restrict__ out) {
    __shared__ short abufH[2 * 8 * 64 * 8];   // 16 KB A-frags hi  [m][kk][ls][j]
    __shared__ short abufL[2 * 8 * 64 * 8];   // 16 KB A-frags lo
    __shared__ float bias_s[KCB];             // 4 KB
    __shared__ float wmax[16][TPB];           // 2 KB
    __shared__ float maxv[TPB];
    __shared__ int   ccnt[TPB];
    __shared__ int   clist[TPB][CAND_MAX];    // 4 KB
    __shared__ int   codes_s[TPB][LVL];       // 1 KB

    const int tid  = threadIdx.x;
    const int w    = tid >> 6;            // wave 0..15 -> cols [w*64, w*64+64)
    const int lane = tid & 63;
    const int tokq = tid >> 5;            // token 0..31 (32-thread group)
    const int c32  = tid & 31;
    const long tok0 = (long)blockIdx.x * TPB;
    const float* xblk = x + tok0 * DIM;

    // residual in registers: dims d = 2*c32 + 64*p + {0,1}, p = 0..3
    double res[8];
    #pragma unroll
    for (int p = 0; p < 4; p++) {
        float2 xv = *(const float2*)(xblk + tokq * DIM + 2 * c32 + 64 * p);
        res[2 * p]     = (double)xv.x;
        res[2 * p + 1] = (double)xv.y;
    }

    for (int l = 0; l < LVL; l++) {
        const float* cbl = cb + (long)l * KCB * DIM;

        // ---- phase 1: A-convert (regs -> bf16 hi/lo frags) + bias stage + reset ----
        {
            const int m = tokq >> 4, tr = tokq & 15;
            #pragma unroll
            for (int p = 0; p < 4; p++) {
                int d = 2 * c32 + 64 * p;
                float fA = (float)res[2 * p], fB = (float)res[2 * p + 1];
                unsigned short hA = f2bf(fA), hB = f2bf(fB);
                unsigned short lA = f2bf(fA - bf2f(hA)), lB = f2bf(fB - bf2f(hB));
                int kk  = d >> 5;
                int ls  = tr + ((d >> 3) & 3) * 16;
                int idx = ((m * 8 + kk) * 64 + ls) * 8 + (d & 7);   // even -> 4B aligned
                *(unsigned*)&abufH[idx] = (unsigned)hA | ((unsigned)hB << 16);
                *(unsigned*)&abufL[idx] = (unsigned)lA | ((unsigned)lB << 16);
            }
        }
        bias_s[tid] = bias[l * KCB + tid];
        if (tid < TPB) ccnt[tid] = 0;
        __syncthreads();

        // ---- phase 2: GEMM score* = r.c - 0.5||c||^2 (2-pass split-bf16) ----
        f32x4 acc[2][4];
        #pragma unroll
        for (int n = 0; n < 4; n++) {
            float b = bias_s[w * 64 + n * 16 + (lane & 15)];
            acc[0][n] = (f32x4){b, b, b, b};
            acc[1][n] = (f32x4){b, b, b, b};
        }
        const short* packW = packed + ((long)(l * 64 + w * 4) * 8) * 512 + lane * 8;
        bf16x8 chvN[4];                               // prefetch buffer (kk+1)
        #pragma unroll
        for (int n = 0; n < 4; n++)
            chvN[n] = *(const bf16x8*)(packW + (long)(n * 8) * 512);
        #pragma unroll
        for (int kk = 0; kk < 8; kk++) {
            bf16x8 chv[4];
            #pragma unroll
            for (int n = 0; n < 4; n++) chv[n] = chvN[n];
            if (kk < 7) {
                #pragma unroll
                for (int n = 0; n < 4; n++)
                    chvN[n] = *(const bf16x8*)(packW + (long)(n * 8 + kk + 1) * 512);
            }
            bf16x8 ah0 = *(const bf16x8*)(abufH + (kk)     * 512 + lane * 8);
            bf16x8 ah1 = *(const bf16x8*)(abufH + (8 + kk) * 512 + lane * 8);
            bf16x8 al0 = *(const bf16x8*)(abufL + (kk)     * 512 + lane * 8);
            bf16x8 al1 = *(const bf16x8*)(abufL + (8 + kk) * 512 + lane * 8);
            #pragma unroll
            for (int n = 0; n < 4; n++) {
                acc[0][n] = __builtin_amdgcn_mfma_f32_16x16x32_bf16(ah0, chv[n], acc[0][n], 0, 0, 0);
                acc[1][n] = __builtin_amdgcn_mfma_f32_16x16x32_bf16(ah1, chv[n], acc[1][n], 0, 0, 0);
                acc[0][n] = __builtin_amdgcn_mfma_f32_16x16x32_bf16(al0, chv[n], acc[0][n], 0, 0, 0);
                acc[1][n] = __builtin_amdgcn_mfma_f32_16x16x32_bf16(al1, chv[n], acc[1][n], 0, 0, 0);
            }
        }

        // ---- wave-level per-token max (C/D: col=lane&15, row=(lane>>4)*4+r) ----
        {
            float bv[2][4];
            #pragma unroll
            for (int m = 0; m < 2; m++)
                #pragma unroll
                for (int r = 0; r < 4; r++) {
                    float v = acc[m][0][r];
                    #pragma unroll
                    for (int n = 1; n < 4; n++) v = fmaxf(v, acc[m][n][r]);
                    bv[m][r] = v;
                }
            #pragma unroll
            for (int off = 1; off < 16; off <<= 1)
                #pragma unroll
                for (int m = 0; m < 2; m++)
                    #pragma unroll
                    for (int r = 0; r < 4; r++)
                        bv[m][r] = fmaxf(bv[m][r], __shfl_xor(bv[m][r], off));
            if ((lane & 15) == 0)
                #pragma unroll
                for (int m = 0; m < 2; m++)
                    #pragma unroll
                    for (int r = 0; r < 4; r++)
                        wmax[w][m * 16 + (lane >> 4) * 4 + r] = bv[m][r];
        }
        __syncthreads();

        // ---- block max ----
        if (tid < TPB) {
            float m = wmax[0][tid];
            #pragma unroll
            for (int ww = 1; ww < 16; ww++) m = fmaxf(m, wmax[ww][tid]);
            maxv[tid] = m;
        }
        __syncthreads();

        // ---- phase 3: candidate scan -> per-token LDS lists ----
        #pragma unroll
        for (int m = 0; m < 2; m++)
            #pragma unroll
            for (int r = 0; r < 4; r++) {
                int tok = m * 16 + (lane >> 4) * 4 + r;
                float thr = maxv[tok] - MARGIN_STAR;
                #pragma unroll
                for (int n = 0; n < 4; n++) {
                    if (acc[m][n][r] >= thr) {
                        int k = w * 64 + n * 16 + (lane & 15);
                        int pos = atomicAdd(&ccnt[tok], 1);
                        if (pos < CAND_MAX) clist[tok][pos] = k;
                    }
                }
            }
        __syncthreads();

        // ---- phase 4: cooperative exact-f64 refine (32 threads/token) + update ----
        int cnt = ccnt[tokq];
        if (cnt > CAND_MAX) cnt = CAND_MAX;
        double bd = 1e300; int bk = KCB;
        for (int j = 0; j < cnt; j++) {
            int k = clist[tokq][j];
            const float* crow = cbl + (long)k * DIM + 2 * c32;
            double s = 0.0;
            #pragma unroll
            for (int p = 0; p < 4; p++) {
                float2 cv = *(const float2*)(crow + 64 * p);
                double a  = res[2 * p]     - (double)cv.x;
                double b2 = res[2 * p + 1] - (double)cv.y;
                s += a * a + b2 * b2;
            }
            #pragma unroll
            for (int off = 1; off < 32; off <<= 1) s += __shfl_xor(s, off);
            if (s < bd || (s == bd && k < bk)) { bd = s; bk = k; }
        }
        if (c32 == 0) codes_s[tokq][l] = bk;
        {
            const float* crow = cbl + (long)bk * DIM + 2 * c32;
            #pragma unroll
            for (int p = 0; p < 4; p++) {
                float2 cv = *(const float2*)(crow + 64 * p);
                res[2 * p]     -= (double)cv.x;
                res[2 * p + 1] -= (double)cv.y;
            }
        }
        __syncthreads();
    }

    // ---- outputs: quantized = x - residual ; codes as float ----
    #pragma unroll
    for (int p = 0; p < 4; p++) {
        int d = 2 * c32 + 64 * p;
        float2 xv = *(const float2*)(xblk + tokq * DIM + d);
        float2 q;
        q.x = (float)((double)xv.x - res[2 * p]);
        q.y = (float)((double)xv.y - res[2 * p + 1]);
        *(float2*)(out + (tok0 + tokq) * DIM + d) = q;
    }
    float* cout = out + (long)N_TOK * DIM;
    if (tid < TPB * LVL) {
        int t = tid >> 3, ll = tid & 7;
        cout[(tok0 + t) * LVL + ll] = (float)codes_s[t][ll];
    }
}

// ================= fallback (f32 path, needs only 32KB ws) =================
__global__ void csq_kernel(const float* __restrict__ cb, float* __restrict__ csq) {
    const int lane = threadIdx.x & 63;
    const int wid  = (blockIdx.x * blockDim.x + threadIdx.x) >> 6;
    const int nw   = (gridDim.x * blockDim.x) >> 6;
    for (int row = wid; row < LVL * KCB; row += nw) {
        float4 c = *(const float4*)(cb + (long)row * DIM + lane * 4);
        float s = c.x * c.x + c.y * c.y + c.z * c.z + c.w * c.w;
        for (int off = 32; off; off >>= 1) s += __shfl_xor(s, off);
        if (lane == 0) csq[row] = s;
    }
}

__global__ __launch_bounds__(256) void rvq_kernel(const float* __restrict__ x,
                                                  const float* __restrict__ cb,
                                                  const float* __restrict__ csq,
                                                  float* __restrict__ out) {
    __shared__ double r64[16 * RPAD];
    __shared__ float  r32[16 * DIM];
    __shared__ float  wval[4][16];
    __shared__ float  minv[16];
    __shared__ unsigned long long dbits[16];
    __shared__ int    dmin_idx[16];
    __shared__ int    codes_s2[16][LVL];

    const int tid  = threadIdx.x;
    const int wave = tid >> 6;
    const int lane = tid & 63;
    const long tok0 = (long)blockIdx.x * 16;
    const float* xblk = x + tok0 * DIM;

    for (int i = 0; i < 16; i++) {
        float v = xblk[i * DIM + tid];
        r64[i * RPAD + tid] = (double)v;
        r32[i * DIM + tid] = v;
    }
    __syncthreads();

    const int k0 = wave * 256 + lane * 4;
    for (int l = 0; l < LVL; l++) {
        const float* cbl = cb + (long)l * KCB * DIM;
        float acc[4][16];
        #pragma unroll
        for (int j = 0; j < 4; j++)
            #pragma unroll
            for (int t = 0; t < 16; t++) acc[j][t] = 0.f;
        for (int d0 = 0; d0 < DIM; d0 += 4) {
            float4 c4[4];
            #pragma unroll
            for (int j = 0; j < 4; j++)
                c4[j] = *(const float4*)(cbl + (long)(k0 + j) * DIM + d0);
            #pragma unroll
            for (int t = 0; t < 16; t++) {
                float4 r4 = *(const float4*)(r32 + t * DIM + d0);
                #pragma unroll
                for (int j = 0; j < 4; j++) {
                    acc[j][t] = fmaf(c4[j].x, r4.x, acc[j][t]);
                    acc[j][t] = fmaf(c4[j].y, r4.y, acc[j][t]);
                    acc[j][t] = fmaf(c4[j].z, r4.z, acc[j][t]);
                    acc[j][t] = fmaf(c4[j].w, r4.w, acc[j][t]);
                }
            }
        }
        float cs[4];
        #pragma unroll
        for (int j = 0; j < 4; j++) cs[j] = csq[l * KCB + k0 + j];
        #pragma unroll
        for (int j = 0; j < 4; j++)
            #pragma unroll
            for (int t = 0; t < 16; t++)
                acc[j][t] = cs[j] - 2.0f * acc[j][t];

        #pragma unroll
        for (int t = 0; t < 16; t++) {
            float bv = acc[0][t];
            #pragma unroll
            for (int j = 1; j < 4; j++) bv = fminf(bv, acc[j][t]);
            for (int off = 1; off < 64; off <<= 1) bv = fminf(bv, __shfl_xor(bv, off));
            if (lane == 0) wval[wave][t] = bv;
        }
        __syncthreads();
        if (tid < 16) {
            float m = wval[0][tid];
            for (int ww = 1; ww < 4; ww++) m = fminf(m, wval[ww][tid]);
            minv[tid] = m;
            dbits[tid] = 0xFFFFFFFFFFFFFFFFULL;
            dmin_idx[tid] = KCB;
        }
        __syncthreads();
        #pragma unroll
        for (int t = 0; t < 16; t++) {
            float thr = minv[t] + MARGIN_F32;
            #pragma unroll
            for (int j = 0; j < 4; j++)
                if (acc[j][t] <= thr) {
                    double d64 = dist64(r64 + t * RPAD, cbl + (long)(k0 + j) * DIM);
                    atomicMin(&dbits[t], (unsigned long long)__double_as_longlong(d64));
                }
        }
        __syncthreads();
        #pragma unroll
        for (int t = 0; t < 16; t++) {
            float thr = minv[t] + MARGIN_F32;
            #pragma unroll
            for (int j = 0; j < 4; j++)
                if (acc[j][t] <= thr) {
                    double d64 = dist64(r64 + t * RPAD, cbl + (long)(k0 + j) * DIM);
                    if ((unsigned long long)__double_as_longlong(d64) == dbits[t])
                        atomicMin(&dmin_idx[t], k0 + j);
                }
        }
        __syncthreads();
        if (tid < 16) codes_s2[tid][l] = dmin_idx[tid];
        for (int i = 0; i < 16; i++) {
            int k = dmin_idx[i];
            float c = cbl[(long)k * DIM + tid];
            double nr = r64[i * RPAD + tid] - (double)c;
            r64[i * RPAD + tid] = nr;
            r32[i * DIM + tid] = (float)nr;
        }
        __syncthreads();
    }
    for (int i = 0; i < 16; i++) {
        double q = (double)xblk[i * DIM + tid] - r64[i * RPAD + tid];
        out[tok0 * DIM + i * DIM + tid] = (float)q;
    }
    float* cout = out + (long)N_TOK * DIM;
    if (tid < 16 * LVL) {
        int t = tid >> 3, ll = tid & 7;
        cout[(tok0 + t) * LVL + ll] = (float)codes_s2[t][ll];
    }
}

extern "C" void kernel_launch(void* const* d_in, const int* in_sizes, int n_in,
                              void* d_out, int out_size, void* d_ws, size_t ws_size,
                              hipStream_t stream) {
    const float* x  = (const float*)d_in[0];
    const float* cb = (const float*)d_in[1];
    const size_t need = (size_t)4 * 1024 * 1024 + 32 * 1024;
    if (ws_size >= need) {
        short* packed = (short*)d_ws;
        float* bias = (float*)((char*)d_ws + (size_t)4 * 1024 * 1024);
        pack_kernel<<<1024, 256, 0, stream>>>(cb, packed);
        bias_kernel<<<32, 256, 0, stream>>>(cb, bias);
        rvq_mfma<<<N_TOK / TPB, THREADS, 0, stream>>>(x, cb, packed, bias, (float*)d_out);
    } else {
        float* csq = (float*)d_ws;
        csq_kernel<<<32, 256, 0, stream>>>(cb, csq);
        rvq_kernel<<<N_TOK / 16, 256, 0, stream>>>(x, cb, csq, (float*)d_out);
    }
}